// Round 7
// baseline (374.406 us; speedup 1.0000x reference)
//
#include <hip/hip_runtime.h>

// Problem: 500 GD steps on a 2-conv model, loss = ||FFT(y)-FFT(yhat)||^2.
// Parseval => loss = 256 * sum (y - yhat)^2 ; mean over batch 1024 => 2c = 0.5.
// yhat[n,w] = beff + sum_{i=(r,a)} A[i] * xpad[n, r, w+a-10],
//   A[r,a] = sum_h k2[h]*k1[r-h+1,a],  beff = b2 + b1*(k2[0]+k2[1]+k2[2]).
// Sufficient stats: XX[63][63], XY[63], Sx[63], Ysum. Train on those; apply.
//
// k_train R7: LDS-resident swizzled matrix (R6) + full VGPR budget
// (__launch_bounds__(64,1), R4) + EXPLICIT 16-chunk stage into named float4s
// so all ds_read_b128 issue back-to-back before the FMA block (R6 at
// VGPR_Count=68 serialized into 8 load->wait->consume pairs, ~1330 cyc/iter).
// Per-iter opaque pin on the swizzle operand keeps the loads inside the loop
// (hoisting = 64 loop-carried floats = the R3-R5 spill disaster, VGPR 48-68
// with scratch reloads hitting L2, invisible in FETCH_SIZE).

#define NB1 4              // batch rows per k_stats block
#define NBLK 256           // 1024 / NB1
#define PSTRIDE 4096       // 3969 XX + 63 XY + 63 Sx + 1 Ysum = 4096
#define ST_OFF (NBLK * PSTRIDE)     // partials end / M begins
#define RHS_OFF (ST_OFF + 4096)     // M is 64*64
#define AF_OFF (RHS_OFF + 64)
// fallback (atomic) layout
#define FB_M 4096
#define FB_RHS 8192
#define FB_AF 8256

// ---------------- stats kernel ----------------
template <int ATOMIC>
__global__ __launch_bounds__(256) void k_stats(const float* __restrict__ in,
                                               float* __restrict__ Pbase) {
    __shared__ float xs[NB1][3][276];   // zero-padded rows: u+10, u in [-10,265]
    __shared__ float ys[NB1][256];
    const int tid = threadIdx.x;
    const int n0 = blockIdx.x * NB1;

    float* xsf = &xs[0][0][0];
    for (int p = tid; p < NB1 * 3 * 276; p += 256) xsf[p] = 0.f;
    __syncthreads();
    for (int p = tid; p < NB1 * 4 * 256; p += 256) {
        int w = p & 255, h = (p >> 8) & 3, n = p >> 10;
        float v = in[((n0 + n) * 4 + h) * 256 + w];
        if (h == 0) ys[n][w] = v;
        else xs[n][h - 1][10 + w] = v;
    }
    __syncthreads();

    const int ti = tid >> 4, tj = tid & 15;
    const int i0 = ti * 4;
    int ir[4], ia[4], jr[4], ja[4];
#pragma unroll
    for (int p = 0; p < 4; ++p) {
        int i = i0 + p; if (i > 62) i = 62;
        ir[p] = i / 21; ia[p] = i % 21;
        int j = p * 16 + tj; if (j > 62) j = 62;
        jr[p] = j / 21; ja[p] = j % 21;
    }
    float acc[4][4] = {{0.f, 0.f, 0.f, 0.f}, {0.f, 0.f, 0.f, 0.f},
                       {0.f, 0.f, 0.f, 0.f}, {0.f, 0.f, 0.f, 0.f}};
    for (int n = 0; n < NB1; ++n) {
        const float* ba0 = &xs[n][ir[0]][ia[0]];
        const float* ba1 = &xs[n][ir[1]][ia[1]];
        const float* ba2 = &xs[n][ir[2]][ia[2]];
        const float* ba3 = &xs[n][ir[3]][ia[3]];
        const float* bb0 = &xs[n][jr[0]][ja[0]];
        const float* bb1 = &xs[n][jr[1]][ja[1]];
        const float* bb2 = &xs[n][jr[2]][ja[2]];
        const float* bb3 = &xs[n][jr[3]][ja[3]];
#pragma unroll 4
        for (int w = 0; w < 256; ++w) {
            float va0 = ba0[w], va1 = ba1[w], va2 = ba2[w], va3 = ba3[w];
            float vb0 = bb0[w], vb1 = bb1[w], vb2 = bb2[w], vb3 = bb3[w];
            acc[0][0] += va0 * vb0; acc[0][1] += va0 * vb1;
            acc[0][2] += va0 * vb2; acc[0][3] += va0 * vb3;
            acc[1][0] += va1 * vb0; acc[1][1] += va1 * vb1;
            acc[1][2] += va1 * vb2; acc[1][3] += va1 * vb3;
            acc[2][0] += va2 * vb0; acc[2][1] += va2 * vb1;
            acc[2][2] += va2 * vb2; acc[2][3] += va2 * vb3;
            acc[3][0] += va3 * vb0; acc[3][1] += va3 * vb1;
            acc[3][2] += va3 * vb2; acc[3][3] += va3 * vb3;
        }
    }
    float* Pb = ATOMIC ? Pbase : (Pbase + blockIdx.x * PSTRIDE);
#pragma unroll
    for (int p = 0; p < 4; ++p)
#pragma unroll
        for (int q = 0; q < 4; ++q) {
            int i = i0 + p, j = q * 16 + tj;
            if (i < 63 && j < 63) {
                if (ATOMIC) unsafeAtomicAdd(&Pb[i * 63 + j], acc[p][q]);
                else Pb[i * 63 + j] = acc[p][q];
            }
        }
    if (tid < 127) {
        float a2 = 0.f;
        int slot;
        if (tid < 63) {
            int r = tid / 21, a = tid % 21;
            for (int n = 0; n < NB1; ++n) {
                const float* xa = &xs[n][r][a];
                const float* yy = ys[n];
                float s = 0.f;
                for (int w = 0; w < 256; ++w) s += xa[w] * yy[w];
                a2 += s;
            }
            slot = 3969 + tid;
        } else if (tid < 126) {
            int e = tid - 63, r = e / 21, a = e % 21;
            for (int n = 0; n < NB1; ++n) {
                const float* xa = &xs[n][r][a];
                float s = 0.f;
                for (int w = 0; w < 256; ++w) s += xa[w];
                a2 += s;
            }
            slot = 4032 + e;
        } else {
            for (int n = 0; n < NB1; ++n) {
                const float* yy = ys[n];
                float s = 0.f;
                for (int w = 0; w < 256; ++w) s += yy[w];
                a2 += s;
            }
            slot = 4095;
        }
        if (ATOMIC) unsafeAtomicAdd(&Pb[slot], a2);
        else Pb[slot] = a2;
    }
}

// ------- deterministic reduction + scatter into augmented M / RHS -------
// M (64x64, row stride 64): rows 0..62 = [XX[i,:], Sx[i]], row 63 = [Sx, NW].
// RHS (64): [XY[0..62], Ysum].
template <int COUNT>
__global__ __launch_bounds__(256) void k_reduce(const float* __restrict__ P,
                                                float* __restrict__ M,
                                                float* __restrict__ RHS) {
    int e = blockIdx.x * 256 + threadIdx.x;  // 0..4095
    double s = 0.0;
    for (int b = 0; b < COUNT; ++b) s += (double)P[b * PSTRIDE + e];
    float f = (float)s;
    if (e < 3969) {
        int i = e / 63, j = e % 63;
        M[i * 64 + j] = f;
    } else if (e < 4032) {
        RHS[e - 3969] = f;                 // XY[i]
    } else if (e < 4095) {
        int i = e - 4032;                  // Sx[i]
        M[i * 64 + 63] = f;
        M[63 * 64 + i] = f;
    } else {
        RHS[63] = f;                       // Ysum
        M[63 * 64 + 63] = 262144.f;        // NW = 1024*256
    }
}

// ---------------- DPP helpers (VALU-pipe cross-lane) ----------------
template <int CTRL>
__device__ __forceinline__ float dpp_sum_step(float v) {
    int moved = __builtin_amdgcn_update_dpp(0, __float_as_int(v), CTRL, 0xf, 0xf, false);
    return v + __int_as_float(moved);
}
__device__ __forceinline__ float wave_sum64(float v) {
    v = dpp_sum_step<0x111>(v);   // row_shr:1
    v = dpp_sum_step<0x112>(v);   // row_shr:2
    v = dpp_sum_step<0x114>(v);   // row_shr:4
    v = dpp_sum_step<0x118>(v);   // row_shr:8
    v = dpp_sum_step<0x142>(v);   // row_bcast:15
    v = dpp_sum_step<0x143>(v);   // row_bcast:31
    return __int_as_float(__builtin_amdgcn_readlane(__float_as_int(v), 63));
}
__device__ __forceinline__ float lane_bcast(float v, int lane) {
    return __int_as_float(__builtin_amdgcn_readlane(__float_as_int(v), lane));
}

// staged matvec macros: LOADC declares a named float4 (logical chunk c read
// through the XOR swizzle); MVC consumes it against 4 readlane broadcasts.
#define LOADC(c) float4 f##c = Mt[c ^ xx];
#define MVC(c, A0, A1, A2, A3) \
    A0 = fmaf(f##c.x, lane_bcast(z, 4 * c + 0), A0); \
    A1 = fmaf(f##c.y, lane_bcast(z, 4 * c + 1), A1); \
    A2 = fmaf(f##c.z, lane_bcast(z, 4 * c + 2), A2); \
    A3 = fmaf(f##c.w, lane_bcast(z, 4 * c + 3), A3);

// ---------------- training: 500 GD steps, one wave, matrix in LDS ------
__global__ __launch_bounds__(64, 1)
__attribute__((amdgpu_waves_per_eu(1)))
void k_train(const float* __restrict__ M,
             const float* __restrict__ RHS,
             const float* __restrict__ k1_in,
             const float* __restrict__ b1_in,
             const float* __restrict__ k2_in,
             const float* __restrict__ b2_in,
             float* __restrict__ AF) {
    // Row t in Ml[t][*]; logical float4 chunk c stored at physical c^(t&15):
    // fixed logical c across 64 lanes covers all 32 banks at 8 words/bank,
    // the b128 conflict-free optimum (measured 0 SQ_LDS_BANK_CONFLICT in R6).
    __shared__ float4 Ml[64][16];
    const int t = threadIdx.x;
    const int x = t & 15;

    const float4* Mrow = (const float4*)(M + t * 64);
#pragma unroll
    for (int j4 = 0; j4 < 16; ++j4) Ml[t][j4 ^ x] = Mrow[j4];
    float XYr = RHS[t];                    // XY[t] | Ysum (t==63)

    // validity masks for the replicated/shifted k1 state
    const bool m_own = (t < 63);
    const bool mu    = (t < 42);
    const bool md    = (t >= 21 && t < 63);
    const bool mpp   = (t < 21);
    const bool mmm   = (t >= 42);

    float k1v = m_own ? k1_in[t] : 0.f;
    float k1u = mu ? k1_in[t + 21] : 0.f;
    float k1d = md ? k1_in[t - 21] : 0.f;
    float k20 = k2_in[0], k21 = k2_in[1], k22 = k2_in[2];
    float b1 = b1_in[0], b2 = b2_in[0];

    __syncthreads();   // one-time; loop is barrier-free

    const float LRf = 1e-7f;
    const float4* Mt = Ml[t];

    for (int it = 0; it < 500; ++it) {
        // opaque swizzle operand: keeps the 16 LDS loads INSIDE the loop
        // (hoisting would create 64 loop-carried floats -> guaranteed spill)
        int xx = x;
        asm volatile("" : "+v"(xx));

        float S = k20 + k21 + k22;
        float beff = b2 + b1 * S;
        float A = k20 * k1u + k21 * k1v + k22 * k1d;
        float z = m_own ? A : beff;   // z[63] = beff

        // stage ALL 16 chunks first: 16 back-to-back ds_read_b128, latency
        // overlapped under the 64 readlane+fma block that follows.
        LOADC(0)  LOADC(1)  LOADC(2)  LOADC(3)
        LOADC(4)  LOADC(5)  LOADC(6)  LOADC(7)
        LOADC(8)  LOADC(9)  LOADC(10) LOADC(11)
        LOADC(12) LOADC(13) LOADC(14) LOADC(15)

        float a0 = 0.f, a1 = 0.f, a2 = 0.f, a3 = 0.f;
        float a4 = 0.f, a5 = 0.f, a6 = 0.f, a7 = 0.f;
        MVC(0,  a0, a1, a2, a3)  MVC(1,  a4, a5, a6, a7)
        MVC(2,  a0, a1, a2, a3)  MVC(3,  a4, a5, a6, a7)
        MVC(4,  a0, a1, a2, a3)  MVC(5,  a4, a5, a6, a7)
        MVC(6,  a0, a1, a2, a3)  MVC(7,  a4, a5, a6, a7)
        MVC(8,  a0, a1, a2, a3)  MVC(9,  a4, a5, a6, a7)
        MVC(10, a0, a1, a2, a3)  MVC(11, a4, a5, a6, a7)
        MVC(12, a0, a1, a2, a3)  MVC(13, a4, a5, a6, a7)
        MVC(14, a0, a1, a2, a3)  MVC(15, a4, a5, a6, a7)

        float dot = ((a0 + a1) + (a2 + a3)) + ((a4 + a5) + (a6 + a7));
        float Gall = 0.5f * (dot - XYr);

        float E = lane_bcast(Gall, 63);
        float Gv = m_own ? Gall : 0.f;

        // c-sums: lane-local products, DPP reductions (VALU pipe)
        float c0 = wave_sum64(k1u * Gv);
        float c1 = wave_sum64(k1v * Gv);
        float c2 = wave_sum64(k1d * Gv);

        // 4 parallel bpermutes for the stencil rows of G
        float Gp  = __shfl(Gv, t + 21);
        float Gm  = __shfl(Gv, t - 21);
        float Gpp = __shfl(Gv, t + 42);
        float Gmm = __shfl(Gv, t - 42);
        float Gp_m  = mu  ? Gp  : 0.f;
        float Gm_m  = (t >= 21) ? Gm : 0.f;
        float Gpp_m = mpp ? Gpp : 0.f;
        float Gmm_m = mmm ? Gmm : 0.f;

        float gk1v = k20 * Gm_m  + k21 * Gv   + k22 * Gp_m;
        float gk1u = k20 * Gv    + k21 * Gp_m + k22 * Gpp_m;
        float gk1d = k20 * Gmm_m + k21 * Gm_m + k22 * Gv;

        float bE = b1 * E;
        k1v -= m_own ? LRf * gk1v : 0.f;
        k1u -= mu    ? LRf * gk1u : 0.f;
        k1d -= md    ? LRf * gk1d : 0.f;
        k20 -= LRf * (bE + c0);
        k21 -= LRf * (bE + c1);
        k22 -= LRf * (bE + c2);
        b1  -= LRf * (S * E);
        b2  -= LRf * E;
    }

    float A = k20 * k1u + k21 * k1v + k22 * k1d;
    AF[t] = m_own ? A : (b2 + b1 * (k20 + k21 + k22));
}

// ---------------- apply: out = y - yhat(final params) ----------------
__global__ __launch_bounds__(256) void k_apply(const float* __restrict__ in,
                                               const float* __restrict__ AF,
                                               float* __restrict__ out) {
    __shared__ float xs[3][276];
    __shared__ float As[64];
    const int n = blockIdx.x, t = threadIdx.x;
    float* xsf = &xs[0][0];
    for (int p = t; p < 3 * 276; p += 256) xsf[p] = 0.f;
    if (t < 64) As[t] = AF[t];
    __syncthreads();
    for (int p = t; p < 3 * 256; p += 256) {
        int r = p >> 8, w = p & 255;
        xs[r][10 + w] = in[(n * 4 + 1 + r) * 256 + w];
    }
    __syncthreads();
    float s = As[63];  // beff
#pragma unroll
    for (int r = 0; r < 3; ++r)
#pragma unroll
        for (int a = 0; a < 21; ++a)
            s += As[r * 21 + a] * xs[r][t + a];
    out[n * 256 + t] = in[(n * 4) * 256 + t] - s;
}

extern "C" void kernel_launch(void* const* d_in, const int* in_sizes, int n_in,
                              void* d_out, int out_size, void* d_ws, size_t ws_size,
                              hipStream_t stream) {
    const float* in = (const float*)d_in[0];
    const float* k1 = (const float*)d_in[1];
    const float* b1 = (const float*)d_in[2];
    const float* k2 = (const float*)d_in[3];
    const float* b2 = (const float*)d_in[4];
    float* out = (float*)d_out;
    float* ws = (float*)d_ws;

    const size_t need = (size_t)(AF_OFF + 64) * sizeof(float);  // ~4.2 MiB
    if (ws_size >= need) {
        float* P   = ws;
        float* M   = ws + ST_OFF;
        float* RHS = ws + RHS_OFF;
        float* AF  = ws + AF_OFF;
        k_stats<0><<<NBLK, 256, 0, stream>>>(in, P);
        k_reduce<NBLK><<<16, 256, 0, stream>>>(P, M, RHS);
        k_train<<<1, 64, 0, stream>>>(M, RHS, k1, b1, k2, b2, AF);
        k_apply<<<1024, 256, 0, stream>>>(in, AF, out);
    } else {
        float* ST0 = ws;
        float* M   = ws + FB_M;
        float* RHS = ws + FB_RHS;
        float* AF  = ws + FB_AF;
        hipMemsetAsync(ST0, 0, PSTRIDE * sizeof(float), stream);
        k_stats<1><<<NBLK, 256, 0, stream>>>(in, ST0);
        k_reduce<1><<<16, 256, 0, stream>>>(ST0, M, RHS);
        k_train<<<1, 64, 0, stream>>>(M, RHS, k1, b1, k2, b2, AF);
        k_apply<<<1024, 256, 0, stream>>>(in, AF, out);
    }
}

// Round 8
// 306.989 us; speedup vs baseline: 1.2196x; 1.2196x over previous
//
#include <hip/hip_runtime.h>

// Problem: 500 GD steps on a 2-conv model, loss = ||FFT(y)-FFT(yhat)||^2.
// Parseval => loss = 256 * sum (y - yhat)^2 ; mean over batch 1024 => 2c = 0.5.
// yhat[n,w] = beff + sum_{i=(r,a)} A[i] * xpad[n, r, w+a-10],
//   A[r,a] = sum_h k2[h]*k1[r-h+1,a],  beff = b2 + b1*(k2[0]+k2[1]+k2[2]).
// Sufficient stats: XX[63][63], XY[63], Sx[63], Ysum. Train on those; apply.
//
// k_train R8: 4-WAVE column-split matvec. R3-R7 proved the single-wave loop
// is pinned at ~1100-1380 cyc/iter: the compiler will not hold the 64-float
// row in VGPRs (VGPR_Count 48-68 across all attempts), and the 64-readlane
// +64-FMA matvec core plus ~70-op scalar tail is issue-bound on one SIMD.
// Structure now: 256 threads = 4 waves; wave w owns matvec columns
// [16w,16w+16) (4 swizzled LDS chunks, pinned loop-invariant addresses ->
// loads stay in-loop, ~1 VALU each; 16 readlane + 16 FMA). Partials combine
// via double-buffered pG[2][4][64] with ONE s_barrier per iteration (WAR
// across iterations is fenced by the *next* barrier). Scalar tail (DPP
// c-sums, 4 pre-addressed ds_bpermute stencil fetches, updates) is
// replicated in all waves -- bitwise identical, no extra sync.

#define NB1 4              // batch rows per k_stats block
#define NBLK 256           // 1024 / NB1
#define PSTRIDE 4096       // 3969 XX + 63 XY + 63 Sx + 1 Ysum = 4096
#define ST_OFF (NBLK * PSTRIDE)     // partials end / M begins
#define RHS_OFF (ST_OFF + 4096)     // M is 64*64
#define AF_OFF (RHS_OFF + 64)
// fallback (atomic) layout
#define FB_M 4096
#define FB_RHS 8192
#define FB_AF 8256

// ---------------- stats kernel ----------------
template <int ATOMIC>
__global__ __launch_bounds__(256) void k_stats(const float* __restrict__ in,
                                               float* __restrict__ Pbase) {
    __shared__ float xs[NB1][3][276];   // zero-padded rows: u+10, u in [-10,265]
    __shared__ float ys[NB1][256];
    const int tid = threadIdx.x;
    const int n0 = blockIdx.x * NB1;

    float* xsf = &xs[0][0][0];
    for (int p = tid; p < NB1 * 3 * 276; p += 256) xsf[p] = 0.f;
    __syncthreads();
    for (int p = tid; p < NB1 * 4 * 256; p += 256) {
        int w = p & 255, h = (p >> 8) & 3, n = p >> 10;
        float v = in[((n0 + n) * 4 + h) * 256 + w];
        if (h == 0) ys[n][w] = v;
        else xs[n][h - 1][10 + w] = v;
    }
    __syncthreads();

    const int ti = tid >> 4, tj = tid & 15;
    const int i0 = ti * 4;
    int ir[4], ia[4], jr[4], ja[4];
#pragma unroll
    for (int p = 0; p < 4; ++p) {
        int i = i0 + p; if (i > 62) i = 62;
        ir[p] = i / 21; ia[p] = i % 21;
        int j = p * 16 + tj; if (j > 62) j = 62;
        jr[p] = j / 21; ja[p] = j % 21;
    }
    float acc[4][4] = {{0.f, 0.f, 0.f, 0.f}, {0.f, 0.f, 0.f, 0.f},
                       {0.f, 0.f, 0.f, 0.f}, {0.f, 0.f, 0.f, 0.f}};
    for (int n = 0; n < NB1; ++n) {
        const float* ba0 = &xs[n][ir[0]][ia[0]];
        const float* ba1 = &xs[n][ir[1]][ia[1]];
        const float* ba2 = &xs[n][ir[2]][ia[2]];
        const float* ba3 = &xs[n][ir[3]][ia[3]];
        const float* bb0 = &xs[n][jr[0]][ja[0]];
        const float* bb1 = &xs[n][jr[1]][ja[1]];
        const float* bb2 = &xs[n][jr[2]][ja[2]];
        const float* bb3 = &xs[n][jr[3]][ja[3]];
#pragma unroll 4
        for (int w = 0; w < 256; ++w) {
            float va0 = ba0[w], va1 = ba1[w], va2 = ba2[w], va3 = ba3[w];
            float vb0 = bb0[w], vb1 = bb1[w], vb2 = bb2[w], vb3 = bb3[w];
            acc[0][0] += va0 * vb0; acc[0][1] += va0 * vb1;
            acc[0][2] += va0 * vb2; acc[0][3] += va0 * vb3;
            acc[1][0] += va1 * vb0; acc[1][1] += va1 * vb1;
            acc[1][2] += va1 * vb2; acc[1][3] += va1 * vb3;
            acc[2][0] += va2 * vb0; acc[2][1] += va2 * vb1;
            acc[2][2] += va2 * vb2; acc[2][3] += va2 * vb3;
            acc[3][0] += va3 * vb0; acc[3][1] += va3 * vb1;
            acc[3][2] += va3 * vb2; acc[3][3] += va3 * vb3;
        }
    }
    float* Pb = ATOMIC ? Pbase : (Pbase + blockIdx.x * PSTRIDE);
#pragma unroll
    for (int p = 0; p < 4; ++p)
#pragma unroll
        for (int q = 0; q < 4; ++q) {
            int i = i0 + p, j = q * 16 + tj;
            if (i < 63 && j < 63) {
                if (ATOMIC) unsafeAtomicAdd(&Pb[i * 63 + j], acc[p][q]);
                else Pb[i * 63 + j] = acc[p][q];
            }
        }
    if (tid < 127) {
        float a2 = 0.f;
        int slot;
        if (tid < 63) {
            int r = tid / 21, a = tid % 21;
            for (int n = 0; n < NB1; ++n) {
                const float* xa = &xs[n][r][a];
                const float* yy = ys[n];
                float s = 0.f;
                for (int w = 0; w < 256; ++w) s += xa[w] * yy[w];
                a2 += s;
            }
            slot = 3969 + tid;
        } else if (tid < 126) {
            int e = tid - 63, r = e / 21, a = e % 21;
            for (int n = 0; n < NB1; ++n) {
                const float* xa = &xs[n][r][a];
                float s = 0.f;
                for (int w = 0; w < 256; ++w) s += xa[w];
                a2 += s;
            }
            slot = 4032 + e;
        } else {
            for (int n = 0; n < NB1; ++n) {
                const float* yy = ys[n];
                float s = 0.f;
                for (int w = 0; w < 256; ++w) s += yy[w];
                a2 += s;
            }
            slot = 4095;
        }
        if (ATOMIC) unsafeAtomicAdd(&Pb[slot], a2);
        else Pb[slot] = a2;
    }
}

// ------- deterministic reduction + scatter into augmented M / RHS -------
// M (64x64, row stride 64): rows 0..62 = [XX[i,:], Sx[i]], row 63 = [Sx, NW].
// RHS (64): [XY[0..62], Ysum].
template <int COUNT>
__global__ __launch_bounds__(256) void k_reduce(const float* __restrict__ P,
                                                float* __restrict__ M,
                                                float* __restrict__ RHS) {
    int e = blockIdx.x * 256 + threadIdx.x;  // 0..4095
    double s = 0.0;
    for (int b = 0; b < COUNT; ++b) s += (double)P[b * PSTRIDE + e];
    float f = (float)s;
    if (e < 3969) {
        int i = e / 63, j = e % 63;
        M[i * 64 + j] = f;
    } else if (e < 4032) {
        RHS[e - 3969] = f;                 // XY[i]
    } else if (e < 4095) {
        int i = e - 4032;                  // Sx[i]
        M[i * 64 + 63] = f;
        M[63 * 64 + i] = f;
    } else {
        RHS[63] = f;                       // Ysum
        M[63 * 64 + 63] = 262144.f;        // NW = 1024*256
    }
}

// ---------------- cross-lane helpers ----------------
template <int CTRL>
__device__ __forceinline__ float dpp_sum_step(float v) {
    int moved = __builtin_amdgcn_update_dpp(0, __float_as_int(v), CTRL, 0xf, 0xf, false);
    return v + __int_as_float(moved);
}
__device__ __forceinline__ float wave_sum64(float v) {
    v = dpp_sum_step<0x111>(v);   // row_shr:1
    v = dpp_sum_step<0x112>(v);   // row_shr:2
    v = dpp_sum_step<0x114>(v);   // row_shr:4
    v = dpp_sum_step<0x118>(v);   // row_shr:8
    v = dpp_sum_step<0x142>(v);   // row_bcast:15
    v = dpp_sum_step<0x143>(v);   // row_bcast:31
    return __int_as_float(__builtin_amdgcn_readlane(__float_as_int(v), 63));
}
__device__ __forceinline__ float lane_bcast(float v, int lane) {
    return __int_as_float(__builtin_amdgcn_readlane(__float_as_int(v), lane));
}
__device__ __forceinline__ float bperm(int byteaddr, float v) {
    return __int_as_float(__builtin_amdgcn_ds_bpermute(byteaddr, __float_as_int(v)));
}

// one GD iteration; BUF selects the pG double-buffer half (compile-time)
#define ITER(BUF) do {                                                        \
    asm volatile("" : "+v"(i0), "+v"(i1), "+v"(i2), "+v"(i3));                \
    float S = k20 + k21 + k22;                                                \
    float beff = b2 + b1 * S;                                                 \
    float A = k20 * k1u + k21 * k1v + k22 * k1d;                              \
    float z = m_own ? A : beff;                                               \
    float4 f0 = Ml4[i0], f1 = Ml4[i1], f2 = Ml4[i2], f3 = Ml4[i3];            \
    float a0 = f0.x * lane_bcast(z, zb + 0);                                  \
    float a1 = f0.y * lane_bcast(z, zb + 1);                                  \
    float a2 = f0.z * lane_bcast(z, zb + 2);                                  \
    float a3 = f0.w * lane_bcast(z, zb + 3);                                  \
    a0 = fmaf(f1.x, lane_bcast(z, zb + 4), a0);                               \
    a1 = fmaf(f1.y, lane_bcast(z, zb + 5), a1);                               \
    a2 = fmaf(f1.z, lane_bcast(z, zb + 6), a2);                               \
    a3 = fmaf(f1.w, lane_bcast(z, zb + 7), a3);                               \
    a0 = fmaf(f2.x, lane_bcast(z, zb + 8), a0);                               \
    a1 = fmaf(f2.y, lane_bcast(z, zb + 9), a1);                               \
    a2 = fmaf(f2.z, lane_bcast(z, zb + 10), a2);                              \
    a3 = fmaf(f2.w, lane_bcast(z, zb + 11), a3);                              \
    a0 = fmaf(f3.x, lane_bcast(z, zb + 12), a0);                              \
    a1 = fmaf(f3.y, lane_bcast(z, zb + 13), a1);                              \
    a2 = fmaf(f3.z, lane_bcast(z, zb + 14), a2);                              \
    a3 = fmaf(f3.w, lane_bcast(z, zb + 15), a3);                              \
    pGs[BUF][w][t] = (a0 + a1) + (a2 + a3);                                   \
    __syncthreads();                                                          \
    float dot = (pGs[BUF][0][t] + pGs[BUF][1][t])                             \
              + (pGs[BUF][2][t] + pGs[BUF][3][t]);                            \
    float Gall = 0.5f * (dot - XYr);                                          \
    float E = lane_bcast(Gall, 63);                                           \
    float Gv = m_own ? Gall : 0.f;                                            \
    float c0 = wave_sum64(k1u * Gv);                                          \
    float c1 = wave_sum64(k1v * Gv);                                          \
    float c2 = wave_sum64(k1d * Gv);                                          \
    float Gp  = bperm(apP, Gv);                                               \
    float Gm  = bperm(apM, Gv);                                               \
    float Gpp = bperm(apPP, Gv);                                              \
    float Gmm = bperm(apMM, Gv);                                              \
    float Gp_m  = mu ? Gp : 0.f;                                              \
    float Gm_m  = (t >= 21) ? Gm : 0.f;                                       \
    float Gpp_m = mpp ? Gpp : 0.f;                                            \
    float Gmm_m = mmm ? Gmm : 0.f;                                            \
    float gk1v = k20 * Gm_m  + k21 * Gv   + k22 * Gp_m;                       \
    float gk1u = k20 * Gv    + k21 * Gp_m + k22 * Gpp_m;                      \
    float gk1d = k20 * Gmm_m + k21 * Gm_m + k22 * Gv;                         \
    float bE = b1 * E;                                                        \
    k1v -= m_own ? LRf * gk1v : 0.f;                                          \
    k1u -= mu    ? LRf * gk1u : 0.f;                                          \
    k1d -= md    ? LRf * gk1d : 0.f;                                          \
    k20 -= LRf * (bE + c0);                                                   \
    k21 -= LRf * (bE + c1);                                                   \
    k22 -= LRf * (bE + c2);                                                   \
    b1  -= LRf * (S * E);                                                     \
    b2  -= LRf * E;                                                           \
} while (0)

// ---------------- training: 500 GD steps, 4 waves ----------------
__global__ __launch_bounds__(256, 1)
void k_train(const float* __restrict__ M,
             const float* __restrict__ RHS,
             const float* __restrict__ k1_in,
             const float* __restrict__ b1_in,
             const float* __restrict__ k2_in,
             const float* __restrict__ b2_in,
             float* __restrict__ AF) {
    // Row t, logical float4 chunk c stored at physical c^(t&15): the 64 lanes
    // of a wave reading one fixed logical chunk cover all 32 banks at
    // 8 words/bank (b128 conflict-free optimum; 0 conflicts measured R6/R7).
    __shared__ float4 Ml[64][16];
    __shared__ float pGs[2][4][64];      // double-buffered cross-wave partials
    const int tid = threadIdx.x;
    const int t = tid & 63;              // lane / row index
    const int w = tid >> 6;              // wave id: owns columns [16w,16w+16)
    const int x = t & 15;

    // stage this wave's 4 column chunks (disjoint across waves)
    const float4* Mrow = (const float4*)(M + t * 64);
#pragma unroll
    for (int c = 0; c < 4; ++c) {
        const int lc = 4 * w + c;
        Ml[t][lc ^ x] = Mrow[lc];
    }
    float XYr = RHS[t];                  // XY[t] | Ysum (t==63)

    const bool m_own = (t < 63);
    const bool mu    = (t < 42);
    const bool md    = (t >= 21 && t < 63);
    const bool mpp   = (t < 21);
    const bool mmm   = (t >= 42);

    // replicated state (identical in all 4 waves; updates are deterministic
    // and instruction-identical -> stays bitwise equal across waves)
    float k1v = m_own ? k1_in[t] : 0.f;
    float k1u = mu ? k1_in[t + 21] : 0.f;
    float k1d = md ? k1_in[t - 21] : 0.f;
    float k20 = k2_in[0], k21 = k2_in[1], k22 = k2_in[2];
    float b1 = b1_in[0], b2 = b2_in[0];

    // loop-invariant addresses: chunk indices (pinned per-iter inside ITER so
    // the LDS loads stay in-loop; the pin emits NO instruction), bpermute
    // byte addrs, readlane column base (wave-uniform -> hoisted to SGPRs).
    const float4* Ml4 = &Ml[0][0];
    int i0 = t * 16 + ((4 * w + 0) ^ x);
    int i1 = t * 16 + ((4 * w + 1) ^ x);
    int i2 = t * 16 + ((4 * w + 2) ^ x);
    int i3 = t * 16 + ((4 * w + 3) ^ x);
    const int zb = 16 * w;
    const int apP  = ((t + 21) & 63) * 4;
    const int apM  = ((t - 21) & 63) * 4;
    const int apPP = ((t + 42) & 63) * 4;
    const int apMM = ((t - 42) & 63) * 4;
    const float LRf = 1e-7f;

    __syncthreads();   // Ml visible to all waves

    // ONE barrier per iteration: write pG[buf] -> barrier -> read pG[buf].
    // The next write to pG[buf] (iter+2) happens after barrier(iter+1),
    // which is after every wave's read of pG[buf] -> no WAR race.
    for (int it = 0; it < 250; ++it) {
        ITER(0);
        ITER(1);
    }

    if (w == 0) {
        float A = k20 * k1u + k21 * k1v + k22 * k1d;
        AF[t] = m_own ? A : (b2 + b1 * (k20 + k21 + k22));
    }
}

// ---------------- apply: out = y - yhat(final params) ----------------
__global__ __launch_bounds__(256) void k_apply(const float* __restrict__ in,
                                               const float* __restrict__ AF,
                                               float* __restrict__ out) {
    __shared__ float xs[3][276];
    __shared__ float As[64];
    const int n = blockIdx.x, t = threadIdx.x;
    float* xsf = &xs[0][0];
    for (int p = t; p < 3 * 276; p += 256) xsf[p] = 0.f;
    if (t < 64) As[t] = AF[t];
    __syncthreads();
    for (int p = t; p < 3 * 256; p += 256) {
        int r = p >> 8, w = p & 255;
        xs[r][10 + w] = in[(n * 4 + 1 + r) * 256 + w];
    }
    __syncthreads();
    float s = As[63];  // beff
#pragma unroll
    for (int r = 0; r < 3; ++r)
#pragma unroll
        for (int a = 0; a < 21; ++a)
            s += As[r * 21 + a] * xs[r][t + a];
    out[n * 256 + t] = in[(n * 4) * 256 + t] - s;
}

extern "C" void kernel_launch(void* const* d_in, const int* in_sizes, int n_in,
                              void* d_out, int out_size, void* d_ws, size_t ws_size,
                              hipStream_t stream) {
    const float* in = (const float*)d_in[0];
    const float* k1 = (const float*)d_in[1];
    const float* b1 = (const float*)d_in[2];
    const float* k2 = (const float*)d_in[3];
    const float* b2 = (const float*)d_in[4];
    float* out = (float*)d_out;
    float* ws = (float*)d_ws;

    const size_t need = (size_t)(AF_OFF + 64) * sizeof(float);  // ~4.2 MiB
    if (ws_size >= need) {
        float* P   = ws;
        float* M   = ws + ST_OFF;
        float* RHS = ws + RHS_OFF;
        float* AF  = ws + AF_OFF;
        k_stats<0><<<NBLK, 256, 0, stream>>>(in, P);
        k_reduce<NBLK><<<16, 256, 0, stream>>>(P, M, RHS);
        k_train<<<1, 256, 0, stream>>>(M, RHS, k1, b1, k2, b2, AF);
        k_apply<<<1024, 256, 0, stream>>>(in, AF, out);
    } else {
        float* ST0 = ws;
        float* M   = ws + FB_M;
        float* RHS = ws + FB_RHS;
        float* AF  = ws + FB_AF;
        hipMemsetAsync(ST0, 0, PSTRIDE * sizeof(float), stream);
        k_stats<1><<<NBLK, 256, 0, stream>>>(in, ST0);
        k_reduce<1><<<16, 256, 0, stream>>>(ST0, M, RHS);
        k_train<<<1, 256, 0, stream>>>(M, RHS, k1, b1, k2, b2, AF);
        k_apply<<<1024, 256, 0, stream>>>(in, AF, out);
    }
}